// Round 5
// baseline (1220.371 us; speedup 1.0000x reference)
//
#include <hip/hip_runtime.h>
#include <hip/hip_bf16.h>

typedef __hip_bfloat16 bf16;
typedef unsigned short ush;

#define BB 2
#define TT 2048
#define DD 1024
#define HH 16
#define DHH 64
#define MM (BB*TT)      // 4096 rows
#define N3 (3*DD)       // 3072

__device__ __forceinline__ float ub2f(ush u){ return __uint_as_float(((unsigned)u) << 16); }
__device__ __forceinline__ bf16  f2b(float x){ return __float2bfloat16(x); }
__device__ __forceinline__ float b2f(bf16 x){ return __bfloat162float(x); }

// ---------------------------------------------------------------------------
// Kernel 1: QKV projection. C[4096,3072] = x[4096,1024] @ w_attn[1024,3072] + b
// f32 in. Epilogue: q -> qws (bf16 ws), k/v -> d_out present regions (FLOAT32).
// ---------------------------------------------------------------------------
__global__ __launch_bounds__(256) void qkv_gemm(
    const float* __restrict__ x, const float* __restrict__ w,
    const float* __restrict__ bias,
    bf16* __restrict__ qws, float* __restrict__ kout, float* __restrict__ vout)
{
    __shared__ __align__(16) float As[16][68];  // [kk][m]
    __shared__ __align__(16) float Bs[16][68];  // [kk][n]

    const int tid = threadIdx.x;
    const int tx = tid & 15, ty = tid >> 4;
    const int row0 = blockIdx.y * 64;
    const int col0 = blockIdx.x * 64;

    float acc[4][4] = {};

    for (int k0 = 0; k0 < DD; k0 += 16) {
        #pragma unroll
        for (int e = 0; e < 4; e++) {
            int t = tid + e * 256;
            int kk = t & 15, i = t >> 4;
            As[kk][i] = x[(row0 + i) * DD + k0 + kk];
        }
        #pragma unroll
        for (int e = 0; e < 4; e++) {
            int t = tid + e * 256;
            int j = t & 63, kk = t >> 6;
            Bs[kk][j] = w[(k0 + kk) * N3 + col0 + j];
        }
        __syncthreads();
        #pragma unroll
        for (int kk = 0; kk < 16; kk++) {
            const float4 av = *(const float4*)&As[kk][ty * 4];
            const float4 bv = *(const float4*)&Bs[kk][tx * 4];
            const float a4[4] = {av.x, av.y, av.z, av.w};
            const float b4[4] = {bv.x, bv.y, bv.z, bv.w};
            #pragma unroll
            for (int i = 0; i < 4; i++)
                #pragma unroll
                for (int j = 0; j < 4; j++)
                    acc[i][j] = fmaf(a4[i], b4[j], acc[i][j]);
        }
        __syncthreads();
    }

    const int which = col0 >> 10;          // 0=q 1=k 2=v
    const int h = (col0 & 1023) >> 6;
    float bv4[4];
    #pragma unroll
    for (int j = 0; j < 4; j++) bv4[j] = bias[col0 + tx * 4 + j];

    if (which == 0) {
        #pragma unroll
        for (int i = 0; i < 4; i++) {
            int r = row0 + ty * 4 + i;
            int b_ = r >> 11, t_ = r & 2047;
            size_t base = (((size_t)(b_ * HH + h)) * TT + t_) * DHH + tx * 4;
            #pragma unroll
            for (int j = 0; j < 4; j++)
                qws[base + j] = f2b(acc[i][j] + bv4[j]);
        }
    } else {
        float* outp = (which == 1) ? kout : vout;
        #pragma unroll
        for (int i = 0; i < 4; i++) {
            int r = row0 + ty * 4 + i;
            int b_ = r >> 11, t_ = r & 2047;
            size_t base = (((size_t)(b_ * HH + h)) * TT + t_) * DHH + tx * 4;
            #pragma unroll
            for (int j = 0; j < 4; j++)
                outp[base + j] = acc[i][j] + bv4[j];
        }
    }
}

// ---------------------------------------------------------------------------
// Kernel 2: causal flash attention. Q from bf16 ws; K/V from FLOAT32 d_out.
// Serial per-row softmax (thread r owns row r). scale=0.25, mask=-1e10.
// Writes merged-head attn (bf16 ws). LDS ~60.5 KB.
// ---------------------------------------------------------------------------
__global__ __launch_bounds__(256) void flash_attn2(
    const bf16* __restrict__ qin, const float* __restrict__ kin,
    const float* __restrict__ vin, bf16* __restrict__ attn)
{
    __shared__ ush   Qs[64][72];   // [r][d] bf16 bits
    __shared__ float Ks[64][68];   // [c][d]
    __shared__ float Vs[64][68];   // [c][d]
    __shared__ float S[64][68];    // [r][c]
    __shared__ float alphas[64];
    __shared__ float invl[64];

    const int tid = threadIdx.x;
    const int tx = tid & 15, ty = tid >> 4;
    const int qi = blockIdx.x;            // 0..31
    const int bh = blockIdx.y;            // 0..31
    const int q0 = qi * 64;

    const ush*   Qp = (const ush*)qin + ((size_t)bh * TT + (size_t)q0) * DHH;
    const float* Kb = kin + (size_t)bh * TT * DHH;
    const float* Vb = vin + (size_t)bh * TT * DHH;

    #pragma unroll
    for (int e = 0; e < 16; e++) {
        int t = tid + e * 256;
        int d = t & 63, r = t >> 6;
        Qs[r][d] = Qp[r * DHH + d];
    }

    float o[4][4] = {};
    float m_old = -1e30f, l_run = 0.f;

    for (int kt = 0; kt <= qi; kt++) {
        const float* Kp = Kb + (size_t)kt * 64 * DHH;
        const float* Vp = Vb + (size_t)kt * 64 * DHH;
        __syncthreads();
        #pragma unroll
        for (int e = 0; e < 16; e++) {
            int t = tid + e * 256;
            int d = t & 63, r = t >> 6;
            Ks[r][d] = Kp[r * DHH + d];
            Vs[r][d] = Vp[r * DHH + d];
        }
        __syncthreads();

        float s[4][4] = {};
        for (int d = 0; d < 64; d++) {
            float qa[4], kb4[4];
            #pragma unroll
            for (int i = 0; i < 4; i++) qa[i]  = ub2f(Qs[ty * 4 + i][d]);
            #pragma unroll
            for (int j = 0; j < 4; j++) kb4[j] = Ks[tx * 4 + j][d];
            #pragma unroll
            for (int i = 0; i < 4; i++)
                #pragma unroll
                for (int j = 0; j < 4; j++)
                    s[i][j] = fmaf(qa[i], kb4[j], s[i][j]);
        }
        const int k0 = kt * 64;
        #pragma unroll
        for (int i = 0; i < 4; i++)
            #pragma unroll
            for (int j = 0; j < 4; j++) {
                float v = s[i][j] * 0.25f;
                if (k0 + tx * 4 + j > q0 + ty * 4 + i) v = -1e10f;
                S[ty * 4 + i][tx * 4 + j] = v;
            }
        __syncthreads();

        if (tid < 64) {
            const int r = tid;
            float mn = m_old;
            for (int c = 0; c < 64; c++) mn = fmaxf(mn, S[r][c]);
            float al = __expf(m_old - mn);
            float ps = 0.f;
            for (int c = 0; c < 64; c++) {
                float p = __expf(S[r][c] - mn);
                S[r][c] = p;
                ps += p;
            }
            l_run = l_run * al + ps;
            m_old = mn;
            alphas[r] = al;
        }
        __syncthreads();

        float al_i[4];
        #pragma unroll
        for (int i = 0; i < 4; i++) al_i[i] = alphas[ty * 4 + i];
        #pragma unroll
        for (int i = 0; i < 4; i++)
            #pragma unroll
            for (int j = 0; j < 4; j++) o[i][j] *= al_i[i];

        for (int k2 = 0; k2 < 64; k2++) {
            float pa[4], vb4[4];
            #pragma unroll
            for (int i = 0; i < 4; i++) pa[i]  = S[ty * 4 + i][k2];
            #pragma unroll
            for (int j = 0; j < 4; j++) vb4[j] = Vs[k2][tx * 4 + j];
            #pragma unroll
            for (int i = 0; i < 4; i++)
                #pragma unroll
                for (int j = 0; j < 4; j++)
                    o[i][j] = fmaf(pa[i], vb4[j], o[i][j]);
        }
    }

    if (tid < 64) invl[tid] = 1.0f / l_run;
    __syncthreads();

    const int b_ = bh >> 4;
    const int h = bh & 15;
    #pragma unroll
    for (int i = 0; i < 4; i++) {
        int t_ = q0 + ty * 4 + i;
        float il = invl[ty * 4 + i];
        size_t base = ((size_t)(b_ * TT + t_)) * DD + h * 64 + tx * 4;
        #pragma unroll
        for (int j = 0; j < 4; j++)
            attn[base + j] = f2b(o[i][j] * il);
    }
}

// ---------------------------------------------------------------------------
// Kernel 3: output projection. out[4096,1024] (FLOAT32) = attn @ w_proj + b
// ---------------------------------------------------------------------------
__global__ __launch_bounds__(256) void proj_gemm(
    const bf16* __restrict__ a, const float* __restrict__ w,
    const float* __restrict__ bias, float* __restrict__ out)
{
    __shared__ __align__(16) float As[16][68];
    __shared__ __align__(16) float Bs[16][68];

    const int tid = threadIdx.x;
    const int tx = tid & 15, ty = tid >> 4;
    const int row0 = blockIdx.y * 64;
    const int col0 = blockIdx.x * 64;

    float acc[4][4] = {};

    for (int k0 = 0; k0 < DD; k0 += 16) {
        #pragma unroll
        for (int e = 0; e < 4; e++) {
            int t = tid + e * 256;
            int kk = t & 15, i = t >> 4;
            As[kk][i] = b2f(a[(row0 + i) * DD + k0 + kk]);
        }
        #pragma unroll
        for (int e = 0; e < 4; e++) {
            int t = tid + e * 256;
            int j = t & 63, kk = t >> 6;
            Bs[kk][j] = w[(k0 + kk) * DD + col0 + j];
        }
        __syncthreads();
        #pragma unroll
        for (int kk = 0; kk < 16; kk++) {
            const float4 av = *(const float4*)&As[kk][ty * 4];
            const float4 bv = *(const float4*)&Bs[kk][tx * 4];
            const float a4[4] = {av.x, av.y, av.z, av.w};
            const float b4[4] = {bv.x, bv.y, bv.z, bv.w};
            #pragma unroll
            for (int i = 0; i < 4; i++)
                #pragma unroll
                for (int j = 0; j < 4; j++)
                    acc[i][j] = fmaf(a4[i], b4[j], acc[i][j]);
        }
        __syncthreads();
    }

    float bv4[4];
    #pragma unroll
    for (int j = 0; j < 4; j++) bv4[j] = bias[col0 + tx * 4 + j];
    #pragma unroll
    for (int i = 0; i < 4; i++) {
        int r = row0 + ty * 4 + i;
        #pragma unroll
        for (int j = 0; j < 4; j++)
            out[(size_t)r * DD + col0 + tx * 4 + j] = acc[i][j] + bv4[j];
    }
}

extern "C" void kernel_launch(void* const* d_in, const int* in_sizes, int n_in,
                              void* d_out, int out_size, void* d_ws, size_t ws_size,
                              hipStream_t stream) {
    // Inputs resolved by size (all distinct) — confirmed f32.
    const float *x = nullptr, *w_attn = nullptr, *b_attn = nullptr,
                *w_proj = nullptr, *b_proj = nullptr;
    for (int i = 0; i < n_in; i++) {
        switch (in_sizes[i]) {
            case 4194304: x      = (const float*)d_in[i]; break;
            case 3145728: w_attn = (const float*)d_in[i]; break;
            case 3072:    b_attn = (const float*)d_in[i]; break;
            case 1048576: w_proj = (const float*)d_in[i]; break;
            case 1024:    b_proj = (const float*)d_in[i]; break;
            default: break;
        }
    }
    if (!x || !w_attn || !b_attn || !w_proj || !b_proj) return;

    // Outputs are FLOAT32 (reference output dtype): a, then present=[k;v]
    float* out_a = (float*)d_out;                      // [B,T,D]
    float* out_k = out_a + (size_t)MM * DD;            // present[0]=k [B,H,T,dh]
    float* out_v = out_k + (size_t)BB * HH * TT * DHH; // present[1]=v

    const size_t need = (size_t)2 * MM * DD * sizeof(bf16);  // 16 MiB (pinned OK)
    if (ws_size < need) return;
    bf16* qws    = (bf16*)d_ws;
    bf16* attnws = qws + (size_t)BB * HH * TT * DHH;

    qkv_gemm<<<dim3(N3 / 64, MM / 64), 256, 0, stream>>>(x, w_attn, b_attn,
                                                         qws, out_k, out_v);
    flash_attn2<<<dim3(TT / 64, BB * HH), 256, 0, stream>>>(qws, out_k, out_v, attnws);
    proj_gemm<<<dim3(DD / 64, MM / 64), 256, 0, stream>>>(attnws, w_proj, b_proj, out_a);
}

// Round 6
// 683.217 us; speedup vs baseline: 1.7862x; 1.7862x over previous
//
#include <hip/hip_runtime.h>
#include <hip/hip_bf16.h>

typedef __hip_bfloat16 bf16;
typedef unsigned short ush;
typedef __attribute__((ext_vector_type(8))) short bf16x8;
typedef __attribute__((ext_vector_type(4))) float f32x4;

#define BB 2
#define TT 2048
#define DD 1024
#define HH 16
#define DHH 64
#define MM (BB*TT)      // 4096 rows
#define N3 (3*DD)       // 3072

__device__ __forceinline__ float ub2f(ush u){ return __uint_as_float(((unsigned)u) << 16); }
__device__ __forceinline__ bf16  f2b(float x){ return __float2bfloat16(x); }
__device__ __forceinline__ float b2f(bf16 x){ return __bfloat162float(x); }
__device__ __forceinline__ ush   f2bu(float x){ bf16 h = __float2bfloat16(x); return *(ush*)&h; }

// ---------------------------------------------------------------------------
// Kernel 1: QKV projection (UNCHANGED from R5 pass). f32 math.
// q -> qws (bf16 ws), k/v -> d_out present regions (f32, exact).
// ---------------------------------------------------------------------------
__global__ __launch_bounds__(256) void qkv_gemm(
    const float* __restrict__ x, const float* __restrict__ w,
    const float* __restrict__ bias,
    bf16* __restrict__ qws, float* __restrict__ kout, float* __restrict__ vout)
{
    __shared__ __align__(16) float As[16][68];
    __shared__ __align__(16) float Bs[16][68];

    const int tid = threadIdx.x;
    const int tx = tid & 15, ty = tid >> 4;
    const int row0 = blockIdx.y * 64;
    const int col0 = blockIdx.x * 64;

    float acc[4][4] = {};

    for (int k0 = 0; k0 < DD; k0 += 16) {
        #pragma unroll
        for (int e = 0; e < 4; e++) {
            int t = tid + e * 256;
            int kk = t & 15, i = t >> 4;
            As[kk][i] = x[(row0 + i) * DD + k0 + kk];
        }
        #pragma unroll
        for (int e = 0; e < 4; e++) {
            int t = tid + e * 256;
            int j = t & 63, kk = t >> 6;
            Bs[kk][j] = w[(k0 + kk) * N3 + col0 + j];
        }
        __syncthreads();
        #pragma unroll
        for (int kk = 0; kk < 16; kk++) {
            const float4 av = *(const float4*)&As[kk][ty * 4];
            const float4 bv = *(const float4*)&Bs[kk][tx * 4];
            const float a4[4] = {av.x, av.y, av.z, av.w};
            const float b4[4] = {bv.x, bv.y, bv.z, bv.w};
            #pragma unroll
            for (int i = 0; i < 4; i++)
                #pragma unroll
                for (int j = 0; j < 4; j++)
                    acc[i][j] = fmaf(a4[i], b4[j], acc[i][j]);
        }
        __syncthreads();
    }

    const int which = col0 >> 10;
    const int h = (col0 & 1023) >> 6;
    float bv4[4];
    #pragma unroll
    for (int j = 0; j < 4; j++) bv4[j] = bias[col0 + tx * 4 + j];

    if (which == 0) {
        #pragma unroll
        for (int i = 0; i < 4; i++) {
            int r = row0 + ty * 4 + i;
            int b_ = r >> 11, t_ = r & 2047;
            size_t base = (((size_t)(b_ * HH + h)) * TT + t_) * DHH + tx * 4;
            #pragma unroll
            for (int j = 0; j < 4; j++)
                qws[base + j] = f2b(acc[i][j] + bv4[j]);
        }
    } else {
        float* outp = (which == 1) ? kout : vout;
        #pragma unroll
        for (int i = 0; i < 4; i++) {
            int r = row0 + ty * 4 + i;
            int b_ = r >> 11, t_ = r & 2047;
            size_t base = (((size_t)(b_ * HH + h)) * TT + t_) * DHH + tx * 4;
            #pragma unroll
            for (int j = 0; j < 4; j++)
                outp[base + j] = acc[i][j] + bv4[j];
        }
    }
}

// ---------------------------------------------------------------------------
// Kernel 2 (NEW): MFMA flash attention. 64 q-rows/block, 64-col k-tiles.
// 4 waves; wave w owns q-rows w*16..w*16+15. mfma_f32_16x16x32_bf16.
// A-frag: A[m=lane&15][k=quad*8+j]; C/D: col=lane&15, row=quad*4+reg.
// Softmax state in registers (4 rows/lane), butterflies over 16-lane groups.
// P goes D-layout -> per-wave LDS -> A-layout (m120-verified transform).
// scale=0.25, mask=-1e10 BEFORE exp (matches ref exactly).
// ---------------------------------------------------------------------------
__global__ __launch_bounds__(256) void flash_attn_mfma(
    const bf16* __restrict__ qin, const float* __restrict__ kin,
    const float* __restrict__ vin, bf16* __restrict__ attn)
{
    __shared__ __align__(16) ush Qs[64][72];      // [q-row][d]   pitch 144B = 9x16B
    __shared__ __align__(16) ush Ks[64][72];      // [k-col][d]
    __shared__ __align__(16) ush Vt[64][72];      // [d][k-col]   (transposed)
    __shared__ __align__(16) ush Ps[4][16][72];   // per-wave P [row][col]

    const int tid  = threadIdx.x;
    const int lane = tid & 63;
    const int w    = tid >> 6;       // wave 0..3
    const int n16  = lane & 15;
    const int quad = lane >> 4;      // 0..3
    const int qi = blockIdx.x;       // 0..31
    const int bh = blockIdx.y;       // 0..31
    const int q0 = qi * 64;

    const ush*   Qp = (const ush*)qin + ((size_t)bh * TT + q0) * DHH;
    const float* Kb = kin + (size_t)bh * TT * DHH;
    const float* Vb = vin + (size_t)bh * TT * DHH;

    // stage Q tile (bf16 bits, contiguous 4096 ush)
    #pragma unroll
    for (int it = 0; it < 4; it++) {
        int idx = (it * 256 + tid) * 4;
        int r = idx >> 6, d = idx & 63;
        *(ushort4*)&Qs[r][d] = *(const ushort4*)&Qp[idx];
    }

    f32x4 o[4];
    #pragma unroll
    for (int db = 0; db < 4; db++) o[db] = (f32x4){0.f, 0.f, 0.f, 0.f};
    float m_old[4] = {-1e30f, -1e30f, -1e30f, -1e30f};
    float l_run[4] = {0.f, 0.f, 0.f, 0.f};

    for (int kt = 0; kt <= qi; kt++) {
        const float* Kp = Kb + (size_t)(kt * 64) * DHH;
        const float* Vp = Vb + (size_t)(kt * 64) * DHH;
        __syncthreads();   // prior tile's MFMA reads of Ks/Vt complete
        // stage K (f32 -> bf16), coalesced reads, [c][d] writes
        #pragma unroll
        for (int it = 0; it < 4; it++) {
            int idx = (it * 256 + tid) * 4;
            int c = idx >> 6, d = idx & 63;
            float4 kv = *(const float4*)&Kp[idx];
            ushort4 kb;
            kb.x = f2bu(kv.x); kb.y = f2bu(kv.y); kb.z = f2bu(kv.z); kb.w = f2bu(kv.w);
            *(ushort4*)&Ks[c][d] = kb;
        }
        // stage V transposed: thread reads V[c][d0..d0+3], writes Vt[d0+j][c]
        #pragma unroll
        for (int it = 0; it < 4; it++) {
            int c = tid & 63, d0 = (tid >> 6) * 4 + it * 16;
            float4 vv = *(const float4*)&Vp[c * 64 + d0];
            Vt[d0 + 0][c] = f2bu(vv.x);
            Vt[d0 + 1][c] = f2bu(vv.y);
            Vt[d0 + 2][c] = f2bu(vv.z);
            Vt[d0 + 3][c] = f2bu(vv.w);
        }
        __syncthreads();

        // S = Q K^T  (wave's 16 rows x 64 cols)
        bf16x8 qa0 = *(const bf16x8*)&Qs[w * 16 + n16][quad * 8];
        bf16x8 qa1 = *(const bf16x8*)&Qs[w * 16 + n16][32 + quad * 8];
        f32x4 s[4];
        #pragma unroll
        for (int cb = 0; cb < 4; cb++) {
            bf16x8 kb0 = *(const bf16x8*)&Ks[cb * 16 + n16][quad * 8];
            bf16x8 kb1 = *(const bf16x8*)&Ks[cb * 16 + n16][32 + quad * 8];
            f32x4 acc = (f32x4){0.f, 0.f, 0.f, 0.f};
            acc = __builtin_amdgcn_mfma_f32_16x16x32_bf16(qa0, kb0, acc, 0, 0, 0);
            acc = __builtin_amdgcn_mfma_f32_16x16x32_bf16(qa1, kb1, acc, 0, 0, 0);
            s[cb] = acc;
        }

        // online softmax, 4 rows per lane (row = quad*4+reg), cols over 16 lanes x 4 cb
        const int grow_base = q0 + w * 16 + quad * 4;
        const int gcol_base = kt * 64 + n16;
        #pragma unroll
        for (int reg = 0; reg < 4; reg++) {
            float sv[4];
            float pm = -1e30f;
            #pragma unroll
            for (int cb = 0; cb < 4; cb++) {
                float v = s[cb][reg] * 0.25f;
                if (gcol_base + cb * 16 > grow_base + reg) v = -1e10f;
                sv[cb] = v;
                pm = fmaxf(pm, v);
            }
            #pragma unroll
            for (int off = 1; off < 16; off <<= 1)
                pm = fmaxf(pm, __shfl_xor(pm, off));
            float mnew = fmaxf(m_old[reg], pm);
            float alpha = __expf(m_old[reg] - mnew);
            float ps = 0.f;
            #pragma unroll
            for (int cb = 0; cb < 4; cb++) {
                float p = __expf(sv[cb] - mnew);
                Ps[w][quad * 4 + reg][cb * 16 + n16] = f2bu(p);
                ps += p;
            }
            #pragma unroll
            for (int off = 1; off < 16; off <<= 1)
                ps += __shfl_xor(ps, off);
            l_run[reg] = l_run[reg] * alpha + ps;
            m_old[reg] = mnew;
            #pragma unroll
            for (int db = 0; db < 4; db++) o[db][reg] *= alpha;
        }
        __syncthreads();   // Ps visible (conservative; also keeps waves in step)

        // O += P V   (A = Ps rows, B = Vt)
        bf16x8 pa0 = *(const bf16x8*)&Ps[w][n16][quad * 8];
        bf16x8 pa1 = *(const bf16x8*)&Ps[w][n16][32 + quad * 8];
        #pragma unroll
        for (int db = 0; db < 4; db++) {
            bf16x8 vb0 = *(const bf16x8*)&Vt[db * 16 + n16][quad * 8];
            bf16x8 vb1 = *(const bf16x8*)&Vt[db * 16 + n16][32 + quad * 8];
            o[db] = __builtin_amdgcn_mfma_f32_16x16x32_bf16(pa0, vb0, o[db], 0, 0, 0);
            o[db] = __builtin_amdgcn_mfma_f32_16x16x32_bf16(pa1, vb1, o[db], 0, 0, 0);
        }
    }

    // epilogue: O / l -> merged-head attn (bf16 ws)
    const int b_ = bh >> 4, h = bh & 15;
    #pragma unroll
    for (int reg = 0; reg < 4; reg++) {
        const float il = 1.0f / l_run[reg];
        const int t_ = q0 + w * 16 + quad * 4 + reg;
        bf16* outr = attn + ((size_t)(b_ * TT + t_)) * DD + h * 64 + n16;
        #pragma unroll
        for (int db = 0; db < 4; db++)
            outr[db * 16] = f2b(o[db][reg] * il);
    }
}

// ---------------------------------------------------------------------------
// Kernel 3: output projection (UNCHANGED from R5 pass). out f32.
// ---------------------------------------------------------------------------
__global__ __launch_bounds__(256) void proj_gemm(
    const bf16* __restrict__ a, const float* __restrict__ w,
    const float* __restrict__ bias, float* __restrict__ out)
{
    __shared__ __align__(16) float As[16][68];
    __shared__ __align__(16) float Bs[16][68];

    const int tid = threadIdx.x;
    const int tx = tid & 15, ty = tid >> 4;
    const int row0 = blockIdx.y * 64;
    const int col0 = blockIdx.x * 64;

    float acc[4][4] = {};

    for (int k0 = 0; k0 < DD; k0 += 16) {
        #pragma unroll
        for (int e = 0; e < 4; e++) {
            int t = tid + e * 256;
            int kk = t & 15, i = t >> 4;
            As[kk][i] = b2f(a[(row0 + i) * DD + k0 + kk]);
        }
        #pragma unroll
        for (int e = 0; e < 4; e++) {
            int t = tid + e * 256;
            int j = t & 63, kk = t >> 6;
            Bs[kk][j] = w[(k0 + kk) * DD + col0 + j];
        }
        __syncthreads();
        #pragma unroll
        for (int kk = 0; kk < 16; kk++) {
            const float4 av = *(const float4*)&As[kk][ty * 4];
            const float4 bv = *(const float4*)&Bs[kk][tx * 4];
            const float a4[4] = {av.x, av.y, av.z, av.w};
            const float b4[4] = {bv.x, bv.y, bv.z, bv.w};
            #pragma unroll
            for (int i = 0; i < 4; i++)
                #pragma unroll
                for (int j = 0; j < 4; j++)
                    acc[i][j] = fmaf(a4[i], b4[j], acc[i][j]);
        }
        __syncthreads();
    }

    float bv4[4];
    #pragma unroll
    for (int j = 0; j < 4; j++) bv4[j] = bias[col0 + tx * 4 + j];
    #pragma unroll
    for (int i = 0; i < 4; i++) {
        int r = row0 + ty * 4 + i;
        #pragma unroll
        for (int j = 0; j < 4; j++)
            out[(size_t)r * DD + col0 + tx * 4 + j] = acc[i][j] + bv4[j];
    }
}

extern "C" void kernel_launch(void* const* d_in, const int* in_sizes, int n_in,
                              void* d_out, int out_size, void* d_ws, size_t ws_size,
                              hipStream_t stream) {
    const float *x = nullptr, *w_attn = nullptr, *b_attn = nullptr,
                *w_proj = nullptr, *b_proj = nullptr;
    for (int i = 0; i < n_in; i++) {
        switch (in_sizes[i]) {
            case 4194304: x      = (const float*)d_in[i]; break;
            case 3145728: w_attn = (const float*)d_in[i]; break;
            case 3072:    b_attn = (const float*)d_in[i]; break;
            case 1048576: w_proj = (const float*)d_in[i]; break;
            case 1024:    b_proj = (const float*)d_in[i]; break;
            default: break;
        }
    }
    if (!x || !w_attn || !b_attn || !w_proj || !b_proj) return;

    float* out_a = (float*)d_out;                      // [B,T,D]
    float* out_k = out_a + (size_t)MM * DD;            // present[0]=k [B,H,T,dh]
    float* out_v = out_k + (size_t)BB * HH * TT * DHH; // present[1]=v

    const size_t need = (size_t)2 * MM * DD * sizeof(bf16);  // 16 MiB
    if (ws_size < need) return;
    bf16* qws    = (bf16*)d_ws;
    bf16* attnws = qws + (size_t)BB * HH * TT * DHH;

    qkv_gemm<<<dim3(N3 / 64, MM / 64), 256, 0, stream>>>(x, w_attn, b_attn,
                                                         qws, out_k, out_v);
    flash_attn_mfma<<<dim3(TT / 64, BB * HH), 256, 0, stream>>>(qws, out_k, out_v, attnws);
    proj_gemm<<<dim3(DD / 64, MM / 64), 256, 0, stream>>>(attnws, w_proj, b_proj, out_a);
}

// Round 7
// 308.745 us; speedup vs baseline: 3.9527x; 2.2129x over previous
//
#include <hip/hip_runtime.h>
#include <hip/hip_bf16.h>

typedef __hip_bfloat16 bf16;
typedef unsigned short ush;
typedef __attribute__((ext_vector_type(8))) short bf16x8;
typedef __attribute__((ext_vector_type(4))) float f32x4;

#define BB 2
#define TT 2048
#define DD 1024
#define HH 16
#define DHH 64
#define MM (BB*TT)      // 4096 rows
#define N3 (3*DD)       // 3072

__device__ __forceinline__ float ub2f(ush u){ return __uint_as_float(((unsigned)u) << 16); }
__device__ __forceinline__ bf16  f2b(float x){ return __float2bfloat16(x); }
__device__ __forceinline__ ush   f2bu(float x){ bf16 h = __float2bfloat16(x); return *(ush*)&h; }

// ---------------------------------------------------------------------------
// Transpose+convert: dst[c][r] = bf16(src[r][c]). src is [R][C] f32.
// 64x64 tiles. Tiny pre-pass (HBM-bound).
// ---------------------------------------------------------------------------
__global__ __launch_bounds__(256) void transpose_cvt(
    const float* __restrict__ src, ush* __restrict__ dst, int R, int C)
{
    __shared__ ush T[64][68];
    const int tid = threadIdx.x;
    const int c0 = blockIdx.x * 64;
    const int r0 = blockIdx.y * 64;

    #pragma unroll
    for (int it = 0; it < 4; it++) {
        int idx = it * 256 + tid;          // 0..1023
        int i = idx >> 4, jf = idx & 15;   // i<64 row, jf float4 along col
        float4 v = *(const float4*)&src[(size_t)(r0 + i) * C + c0 + jf * 4];
        T[jf * 4 + 0][i] = f2bu(v.x);
        T[jf * 4 + 1][i] = f2bu(v.y);
        T[jf * 4 + 2][i] = f2bu(v.z);
        T[jf * 4 + 3][i] = f2bu(v.w);
    }
    __syncthreads();
    #pragma unroll
    for (int it = 0; it < 4; it++) {
        int idx = it * 256 + tid;          // 0..1023
        int j = idx >> 4, i4 = idx & 15;   // j<64 dst row, i4 ushort4 along r
        *(ushort4*)&dst[(size_t)(c0 + j) * R + r0 + i4 * 4] =
            *(const ushort4*)&T[j][i4 * 4];
    }
}

// ---------------------------------------------------------------------------
// Kernel 1: QKV MFMA GEMM. C[4096,3072] = x @ w_attn + b.
// A: x f32 -> bf16 converted during staging. B: wT bf16 [n][k] (pre-transposed).
// 128x128 tile, BK=32, 4 waves in 2x2, each 64x64 via 16 x mfma 16x16x32.
// Epilogue scatter: q->qws bf16, k/v->d_out f32 [B,H,T,dh].
// ---------------------------------------------------------------------------
__global__ __launch_bounds__(256) void qkv_mfma(
    const float* __restrict__ x, const ush* __restrict__ wT,
    const float* __restrict__ bias,
    bf16* __restrict__ qws, float* __restrict__ kout, float* __restrict__ vout)
{
    __shared__ __align__(16) ush As[128][40];   // [m][k] pitch 80B (5x16B)
    __shared__ __align__(16) ush Bs[128][40];   // [n][k]

    const int tid  = threadIdx.x;
    const int lane = tid & 63;
    const int w    = tid >> 6;
    const int n16  = lane & 15;
    const int quad = lane >> 4;
    const int row0 = blockIdx.y * 128;
    const int col0 = blockIdx.x * 128;
    const int wrow = (w >> 1) * 64;
    const int wcol = (w & 1) * 64;

    f32x4 acc[4][4];
    #pragma unroll
    for (int mb = 0; mb < 4; mb++)
        #pragma unroll
        for (int nb = 0; nb < 4; nb++) acc[mb][nb] = (f32x4){0.f,0.f,0.f,0.f};

    for (int kk0 = 0; kk0 < DD; kk0 += 32) {
        __syncthreads();
        // A: 128x32 f32 -> bf16
        #pragma unroll
        for (int it = 0; it < 4; it++) {
            int idx = it * 256 + tid;         // 0..1023
            int m = idx >> 3, kf = idx & 7;
            float4 v = *(const float4*)&x[(size_t)(row0 + m) * DD + kk0 + kf * 4];
            ushort4 u;
            u.x = f2bu(v.x); u.y = f2bu(v.y); u.z = f2bu(v.z); u.w = f2bu(v.w);
            *(ushort4*)&As[m][kf * 4] = u;
        }
        // B: 128 rows x 32 k of wT (bf16), 16B chunks
        #pragma unroll
        for (int it = 0; it < 2; it++) {
            int idx = it * 256 + tid;         // 0..511
            int n = idx >> 2, kc = idx & 3;
            *(bf16x8*)&Bs[n][kc * 8] =
                *(const bf16x8*)&wT[(size_t)(col0 + n) * DD + kk0 + kc * 8];
        }
        __syncthreads();

        bf16x8 af[4];
        #pragma unroll
        for (int mb = 0; mb < 4; mb++)
            af[mb] = *(const bf16x8*)&As[wrow + mb * 16 + n16][quad * 8];
        #pragma unroll
        for (int nb = 0; nb < 4; nb++) {
            bf16x8 bfr = *(const bf16x8*)&Bs[wcol + nb * 16 + n16][quad * 8];
            #pragma unroll
            for (int mb = 0; mb < 4; mb++)
                acc[mb][nb] = __builtin_amdgcn_mfma_f32_16x16x32_bf16(
                    af[mb], bfr, acc[mb][nb], 0, 0, 0);
        }
    }

    // epilogue: C/D layout col=n16, row=quad*4+reg
    #pragma unroll
    for (int nb = 0; nb < 4; nb++) {
        const int gc = col0 + wcol + nb * 16 + n16;
        const float bv = bias[gc];
        const int which = gc >> 10;
        const int h = (gc & 1023) >> 6;
        const int d = gc & 63;
        #pragma unroll
        for (int mb = 0; mb < 4; mb++) {
            #pragma unroll
            for (int reg = 0; reg < 4; reg++) {
                const int gr = row0 + wrow + mb * 16 + quad * 4 + reg;
                const int b_ = gr >> 11, t_ = gr & 2047;
                const size_t base = (((size_t)(b_ * HH + h)) * TT + t_) * DHH + d;
                const float v = acc[mb][nb][reg] + bv;
                if (which == 0)      qws[base] = f2b(v);
                else if (which == 1) kout[base] = v;
                else                 vout[base] = v;
            }
        }
    }
}

// ---------------------------------------------------------------------------
// Kernel 2: MFMA flash attention (UNCHANGED from R6 pass).
// ---------------------------------------------------------------------------
__global__ __launch_bounds__(256) void flash_attn_mfma(
    const bf16* __restrict__ qin, const float* __restrict__ kin,
    const float* __restrict__ vin, bf16* __restrict__ attn)
{
    __shared__ __align__(16) ush Qs[64][72];
    __shared__ __align__(16) ush Ks[64][72];
    __shared__ __align__(16) ush Vt[64][72];
    __shared__ __align__(16) ush Ps[4][16][72];

    const int tid  = threadIdx.x;
    const int lane = tid & 63;
    const int w    = tid >> 6;
    const int n16  = lane & 15;
    const int quad = lane >> 4;
    const int qi = blockIdx.x;
    const int bh = blockIdx.y;
    const int q0 = qi * 64;

    const ush*   Qp = (const ush*)qin + ((size_t)bh * TT + q0) * DHH;
    const float* Kb = kin + (size_t)bh * TT * DHH;
    const float* Vb = vin + (size_t)bh * TT * DHH;

    #pragma unroll
    for (int it = 0; it < 4; it++) {
        int idx = (it * 256 + tid) * 4;
        int r = idx >> 6, d = idx & 63;
        *(ushort4*)&Qs[r][d] = *(const ushort4*)&Qp[idx];
    }

    f32x4 o[4];
    #pragma unroll
    for (int db = 0; db < 4; db++) o[db] = (f32x4){0.f, 0.f, 0.f, 0.f};
    float m_old[4] = {-1e30f, -1e30f, -1e30f, -1e30f};
    float l_run[4] = {0.f, 0.f, 0.f, 0.f};

    for (int kt = 0; kt <= qi; kt++) {
        const float* Kp = Kb + (size_t)(kt * 64) * DHH;
        const float* Vp = Vb + (size_t)(kt * 64) * DHH;
        __syncthreads();
        #pragma unroll
        for (int it = 0; it < 4; it++) {
            int idx = (it * 256 + tid) * 4;
            int c = idx >> 6, d = idx & 63;
            float4 kv = *(const float4*)&Kp[idx];
            ushort4 kb;
            kb.x = f2bu(kv.x); kb.y = f2bu(kv.y); kb.z = f2bu(kv.z); kb.w = f2bu(kv.w);
            *(ushort4*)&Ks[c][d] = kb;
        }
        #pragma unroll
        for (int it = 0; it < 4; it++) {
            int c = tid & 63, d0 = (tid >> 6) * 4 + it * 16;
            float4 vv = *(const float4*)&Vp[c * 64 + d0];
            Vt[d0 + 0][c] = f2bu(vv.x);
            Vt[d0 + 1][c] = f2bu(vv.y);
            Vt[d0 + 2][c] = f2bu(vv.z);
            Vt[d0 + 3][c] = f2bu(vv.w);
        }
        __syncthreads();

        bf16x8 qa0 = *(const bf16x8*)&Qs[w * 16 + n16][quad * 8];
        bf16x8 qa1 = *(const bf16x8*)&Qs[w * 16 + n16][32 + quad * 8];
        f32x4 s[4];
        #pragma unroll
        for (int cb = 0; cb < 4; cb++) {
            bf16x8 kb0 = *(const bf16x8*)&Ks[cb * 16 + n16][quad * 8];
            bf16x8 kb1 = *(const bf16x8*)&Ks[cb * 16 + n16][32 + quad * 8];
            f32x4 acc = (f32x4){0.f, 0.f, 0.f, 0.f};
            acc = __builtin_amdgcn_mfma_f32_16x16x32_bf16(qa0, kb0, acc, 0, 0, 0);
            acc = __builtin_amdgcn_mfma_f32_16x16x32_bf16(qa1, kb1, acc, 0, 0, 0);
            s[cb] = acc;
        }

        const int grow_base = q0 + w * 16 + quad * 4;
        const int gcol_base = kt * 64 + n16;
        #pragma unroll
        for (int reg = 0; reg < 4; reg++) {
            float sv[4];
            float pm = -1e30f;
            #pragma unroll
            for (int cb = 0; cb < 4; cb++) {
                float v = s[cb][reg] * 0.25f;
                if (gcol_base + cb * 16 > grow_base + reg) v = -1e10f;
                sv[cb] = v;
                pm = fmaxf(pm, v);
            }
            #pragma unroll
            for (int off = 1; off < 16; off <<= 1)
                pm = fmaxf(pm, __shfl_xor(pm, off));
            float mnew = fmaxf(m_old[reg], pm);
            float alpha = __expf(m_old[reg] - mnew);
            float ps = 0.f;
            #pragma unroll
            for (int cb = 0; cb < 4; cb++) {
                float p = __expf(sv[cb] - mnew);
                Ps[w][quad * 4 + reg][cb * 16 + n16] = f2bu(p);
                ps += p;
            }
            #pragma unroll
            for (int off = 1; off < 16; off <<= 1)
                ps += __shfl_xor(ps, off);
            l_run[reg] = l_run[reg] * alpha + ps;
            m_old[reg] = mnew;
            #pragma unroll
            for (int db = 0; db < 4; db++) o[db][reg] *= alpha;
        }
        __syncthreads();

        bf16x8 pa0 = *(const bf16x8*)&Ps[w][n16][quad * 8];
        bf16x8 pa1 = *(const bf16x8*)&Ps[w][n16][32 + quad * 8];
        #pragma unroll
        for (int db = 0; db < 4; db++) {
            bf16x8 vb0 = *(const bf16x8*)&Vt[db * 16 + n16][quad * 8];
            bf16x8 vb1 = *(const bf16x8*)&Vt[db * 16 + n16][32 + quad * 8];
            o[db] = __builtin_amdgcn_mfma_f32_16x16x32_bf16(pa0, vb0, o[db], 0, 0, 0);
            o[db] = __builtin_amdgcn_mfma_f32_16x16x32_bf16(pa1, vb1, o[db], 0, 0, 0);
        }
    }

    const int b_ = bh >> 4, h = bh & 15;
    #pragma unroll
    for (int reg = 0; reg < 4; reg++) {
        const float il = 1.0f / l_run[reg];
        const int t_ = q0 + w * 16 + quad * 4 + reg;
        bf16* outr = attn + ((size_t)(b_ * TT + t_)) * DD + h * 64 + n16;
        #pragma unroll
        for (int db = 0; db < 4; db++)
            outr[db * 16] = f2b(o[db][reg] * il);
    }
}

// ---------------------------------------------------------------------------
// Kernel 3: proj MFMA GEMM. out[4096,1024] f32 = attn(bf16) @ w_proj + b.
// A: attnws bf16 natural. B: wpT bf16 [n][k]. Same structure as qkv_mfma.
// ---------------------------------------------------------------------------
__global__ __launch_bounds__(256) void proj_mfma(
    const ush* __restrict__ a, const ush* __restrict__ wpT,
    const float* __restrict__ bias, float* __restrict__ out)
{
    __shared__ __align__(16) ush As[128][40];
    __shared__ __align__(16) ush Bs[128][40];

    const int tid  = threadIdx.x;
    const int lane = tid & 63;
    const int w    = tid >> 6;
    const int n16  = lane & 15;
    const int quad = lane >> 4;
    const int row0 = blockIdx.y * 128;
    const int col0 = blockIdx.x * 128;
    const int wrow = (w >> 1) * 64;
    const int wcol = (w & 1) * 64;

    f32x4 acc[4][4];
    #pragma unroll
    for (int mb = 0; mb < 4; mb++)
        #pragma unroll
        for (int nb = 0; nb < 4; nb++) acc[mb][nb] = (f32x4){0.f,0.f,0.f,0.f};

    for (int kk0 = 0; kk0 < DD; kk0 += 32) {
        __syncthreads();
        #pragma unroll
        for (int it = 0; it < 2; it++) {
            int idx = it * 256 + tid;
            int m = idx >> 2, kc = idx & 3;
            *(bf16x8*)&As[m][kc * 8] =
                *(const bf16x8*)&a[(size_t)(row0 + m) * DD + kk0 + kc * 8];
        }
        #pragma unroll
        for (int it = 0; it < 2; it++) {
            int idx = it * 256 + tid;
            int n = idx >> 2, kc = idx & 3;
            *(bf16x8*)&Bs[n][kc * 8] =
                *(const bf16x8*)&wpT[(size_t)(col0 + n) * DD + kk0 + kc * 8];
        }
        __syncthreads();

        bf16x8 af[4];
        #pragma unroll
        for (int mb = 0; mb < 4; mb++)
            af[mb] = *(const bf16x8*)&As[wrow + mb * 16 + n16][quad * 8];
        #pragma unroll
        for (int nb = 0; nb < 4; nb++) {
            bf16x8 bfr = *(const bf16x8*)&Bs[wcol + nb * 16 + n16][quad * 8];
            #pragma unroll
            for (int mb = 0; mb < 4; mb++)
                acc[mb][nb] = __builtin_amdgcn_mfma_f32_16x16x32_bf16(
                    af[mb], bfr, acc[mb][nb], 0, 0, 0);
        }
    }

    #pragma unroll
    for (int nb = 0; nb < 4; nb++) {
        const int gc = col0 + wcol + nb * 16 + n16;
        const float bv = bias[gc];
        #pragma unroll
        for (int mb = 0; mb < 4; mb++) {
            #pragma unroll
            for (int reg = 0; reg < 4; reg++) {
                const int gr = row0 + wrow + mb * 16 + quad * 4 + reg;
                out[(size_t)gr * DD + gc] = acc[mb][nb][reg] + bv;
            }
        }
    }
}

extern "C" void kernel_launch(void* const* d_in, const int* in_sizes, int n_in,
                              void* d_out, int out_size, void* d_ws, size_t ws_size,
                              hipStream_t stream) {
    const float *x = nullptr, *w_attn = nullptr, *b_attn = nullptr,
                *w_proj = nullptr, *b_proj = nullptr;
    for (int i = 0; i < n_in; i++) {
        switch (in_sizes[i]) {
            case 4194304: x      = (const float*)d_in[i]; break;
            case 3145728: w_attn = (const float*)d_in[i]; break;
            case 3072:    b_attn = (const float*)d_in[i]; break;
            case 1048576: w_proj = (const float*)d_in[i]; break;
            case 1024:    b_proj = (const float*)d_in[i]; break;
            default: break;
        }
    }
    if (!x || !w_attn || !b_attn || !w_proj || !b_proj) return;

    float* out_a = (float*)d_out;                      // [B,T,D]
    float* out_k = out_a + (size_t)MM * DD;            // present[0]=k
    float* out_v = out_k + (size_t)BB * HH * TT * DHH; // present[1]=v

    // Workspace (16 MiB, liveness-aliased):
    //  [0,6MB)  wT   (w_attn^T bf16)  — dead after qkv_mfma
    //  [0,8MB)  attn (bf16)           — written by flash, read by proj
    //  [8,16MB) qws  (bf16)           — dead after flash
    //  [8,10MB) wpT  (w_proj^T bf16)  — written after flash, read by proj
    const size_t need = (size_t)16 * 1024 * 1024;
    if (ws_size < need) return;
    char* wsc = (char*)d_ws;
    ush*  wT     = (ush*)(wsc + 0);
    bf16* attnws = (bf16*)(wsc + 0);
    bf16* qws    = (bf16*)(wsc + 8 * 1024 * 1024);
    ush*  wpT    = (ush*)(wsc + 8 * 1024 * 1024);

    transpose_cvt<<<dim3(N3 / 64, DD / 64), 256, 0, stream>>>(w_attn, wT, DD, N3);
    qkv_mfma<<<dim3(N3 / 128, MM / 128), 256, 0, stream>>>(x, wT, b_attn,
                                                           qws, out_k, out_v);
    flash_attn_mfma<<<dim3(TT / 64, BB * HH), 256, 0, stream>>>(qws, out_k, out_v, attnws);
    transpose_cvt<<<dim3(DD / 64, DD / 64), 256, 0, stream>>>(w_proj, wpT, DD, DD);
    proj_mfma<<<dim3(DD / 128, MM / 128), 256, 0, stream>>>((const ush*)attnws, wpT,
                                                            b_proj, out_a);
}

// Round 8
// 265.827 us; speedup vs baseline: 4.5908x; 1.1614x over previous
//
#include <hip/hip_runtime.h>
#include <hip/hip_bf16.h>

typedef __hip_bfloat16 bf16;
typedef unsigned short ush;
typedef __attribute__((ext_vector_type(8))) short bf16x8;
typedef __attribute__((ext_vector_type(4))) float f32x4;

#define BB 2
#define TT 2048
#define DD 1024
#define HH 16
#define DHH 64
#define MM (BB*TT)      // 4096 rows
#define N3 (3*DD)       // 3072

__device__ __forceinline__ bf16  f2b(float x){ return __float2bfloat16(x); }
__device__ __forceinline__ ush   f2bu(float x){ bf16 h = __float2bfloat16(x); return *(ush*)&h; }

// ---------------------------------------------------------------------------
// Transpose+convert: dst[c][r] = bf16(src[r][c]). src is [R][C] f32.
// ---------------------------------------------------------------------------
__global__ __launch_bounds__(256) void transpose_cvt(
    const float* __restrict__ src, ush* __restrict__ dst, int R, int C)
{
    __shared__ ush T[64][68];
    const int tid = threadIdx.x;
    const int c0 = blockIdx.x * 64;
    const int r0 = blockIdx.y * 64;

    #pragma unroll
    for (int it = 0; it < 4; it++) {
        int idx = it * 256 + tid;
        int i = idx >> 4, jf = idx & 15;
        float4 v = *(const float4*)&src[(size_t)(r0 + i) * C + c0 + jf * 4];
        T[jf * 4 + 0][i] = f2bu(v.x);
        T[jf * 4 + 1][i] = f2bu(v.y);
        T[jf * 4 + 2][i] = f2bu(v.z);
        T[jf * 4 + 3][i] = f2bu(v.w);
    }
    __syncthreads();
    #pragma unroll
    for (int it = 0; it < 4; it++) {
        int idx = it * 256 + tid;
        int j = idx >> 4, i4 = idx & 15;
        *(ushort4*)&dst[(size_t)(c0 + j) * R + r0 + i4 * 4] =
            *(const ushort4*)&T[j][i4 * 4];
    }
}

// ---------------------------------------------------------------------------
// Kernel 1: QKV MFMA GEMM. 128x128 tile, BK=32, 4 waves 2x2.
// Scatter: q->qws bf16; k->out_k f32 (+kbf bf16 if write_bf); v->out_v f32
// (+vtb bf16 TRANSPOSED [bh][d][t] if write_bf).
// ---------------------------------------------------------------------------
__global__ __launch_bounds__(256) void qkv_mfma(
    const float* __restrict__ x, const ush* __restrict__ wT,
    const float* __restrict__ bias,
    bf16* __restrict__ qws, float* __restrict__ kout, float* __restrict__ vout,
    ush* __restrict__ kbf, ush* __restrict__ vtb, int write_bf)
{
    __shared__ __align__(16) ush As[128][40];
    __shared__ __align__(16) ush Bs[128][40];

    const int tid  = threadIdx.x;
    const int lane = tid & 63;
    const int w    = tid >> 6;
    const int n16  = lane & 15;
    const int quad = lane >> 4;
    const int row0 = blockIdx.y * 128;
    const int col0 = blockIdx.x * 128;
    const int wrow = (w >> 1) * 64;
    const int wcol = (w & 1) * 64;

    f32x4 acc[4][4];
    #pragma unroll
    for (int mb = 0; mb < 4; mb++)
        #pragma unroll
        for (int nb = 0; nb < 4; nb++) acc[mb][nb] = (f32x4){0.f,0.f,0.f,0.f};

    for (int kk0 = 0; kk0 < DD; kk0 += 32) {
        __syncthreads();
        #pragma unroll
        for (int it = 0; it < 4; it++) {
            int idx = it * 256 + tid;
            int m = idx >> 3, kf = idx & 7;
            float4 v = *(const float4*)&x[(size_t)(row0 + m) * DD + kk0 + kf * 4];
            ushort4 u;
            u.x = f2bu(v.x); u.y = f2bu(v.y); u.z = f2bu(v.z); u.w = f2bu(v.w);
            *(ushort4*)&As[m][kf * 4] = u;
        }
        #pragma unroll
        for (int it = 0; it < 2; it++) {
            int idx = it * 256 + tid;
            int n = idx >> 2, kc = idx & 3;
            *(bf16x8*)&Bs[n][kc * 8] =
                *(const bf16x8*)&wT[(size_t)(col0 + n) * DD + kk0 + kc * 8];
        }
        __syncthreads();

        bf16x8 af[4];
        #pragma unroll
        for (int mb = 0; mb < 4; mb++)
            af[mb] = *(const bf16x8*)&As[wrow + mb * 16 + n16][quad * 8];
        #pragma unroll
        for (int nb = 0; nb < 4; nb++) {
            bf16x8 bfr = *(const bf16x8*)&Bs[wcol + nb * 16 + n16][quad * 8];
            #pragma unroll
            for (int mb = 0; mb < 4; mb++)
                acc[mb][nb] = __builtin_amdgcn_mfma_f32_16x16x32_bf16(
                    af[mb], bfr, acc[mb][nb], 0, 0, 0);
        }
    }

    #pragma unroll
    for (int nb = 0; nb < 4; nb++) {
        const int gc = col0 + wcol + nb * 16 + n16;
        const float bv = bias[gc];
        const int which = gc >> 10;
        const int h = (gc & 1023) >> 6;
        const int d = gc & 63;
        #pragma unroll
        for (int mb = 0; mb < 4; mb++) {
            float vv[4];
            #pragma unroll
            for (int reg = 0; reg < 4; reg++) vv[reg] = acc[mb][nb][reg] + bv;
            const int gr0 = row0 + wrow + mb * 16 + quad * 4;  // 4 consecutive rows
            const int b_ = gr0 >> 11, t0 = gr0 & 2047;
            const int bh = b_ * HH + h;
            const size_t tbase = ((size_t)bh * TT + t0) * DHH + d;
            if (which == 0) {
                #pragma unroll
                for (int reg = 0; reg < 4; reg++)
                    qws[tbase + (size_t)reg * DHH] = f2b(vv[reg]);
            } else if (which == 1) {
                #pragma unroll
                for (int reg = 0; reg < 4; reg++) kout[tbase + (size_t)reg * DHH] = vv[reg];
                if (write_bf) {
                    #pragma unroll
                    for (int reg = 0; reg < 4; reg++)
                        kbf[tbase + (size_t)reg * DHH] = f2bu(vv[reg]);
                }
            } else {
                #pragma unroll
                for (int reg = 0; reg < 4; reg++) vout[tbase + (size_t)reg * DHH] = vv[reg];
                if (write_bf) {
                    ushort4 u;
                    u.x = f2bu(vv[0]); u.y = f2bu(vv[1]);
                    u.z = f2bu(vv[2]); u.w = f2bu(vv[3]);
                    *(ushort4*)&vtb[((size_t)bh * DHH + d) * TT + t0] = u;
                }
            }
        }
    }
}

// ---------------------------------------------------------------------------
// Kernel 2 FAST PATH: bf16 K / V^T precomputed. Block = qi-pair {bx, 31-bx}
// (33 k-tiles per block, perfectly balanced). 2 barriers/tile; Ps is
// own-wave (no barrier). Math identical to verified R6 kernel.
// ---------------------------------------------------------------------------
__global__ __launch_bounds__(256) void flash_attn_bf16(
    const ush* __restrict__ qin, const ush* __restrict__ kbf,
    const ush* __restrict__ vtb, bf16* __restrict__ attn)
{
    __shared__ __align__(16) ush Qs[64][72];
    __shared__ __align__(16) ush Ks[64][72];
    __shared__ __align__(16) ush Vt[64][72];
    __shared__ __align__(16) ush Ps[4][16][72];

    const int tid  = threadIdx.x;
    const int lane = tid & 63;
    const int w    = tid >> 6;
    const int n16  = lane & 15;
    const int quad = lane >> 4;
    const int bx = blockIdx.x;       // 0..15
    const int bh = blockIdx.y;       // 0..31
    const ush* Qb  = qin + (size_t)bh * TT * DHH;
    const ush* Kb  = kbf + (size_t)bh * TT * DHH;
    const ush* Vtb = vtb + (size_t)bh * DHH * TT;
    const int b_ = bh >> 4, h = bh & 15;

    #pragma unroll
    for (int strip = 0; strip < 2; strip++) {
        const int qi = strip ? (31 - bx) : bx;
        const int q0 = qi * 64;

        __syncthreads();   // all waves done with previous strip's LDS
        // stage Q tile
        const ush* Qp = Qb + (size_t)q0 * DHH;
        #pragma unroll
        for (int it = 0; it < 2; it++) {
            int chunk = it * 256 + tid;          // 0..511
            int r = chunk >> 3, c8 = (chunk & 7) * 8;
            *(bf16x8*)&Qs[r][c8] = *(const bf16x8*)&Qp[r * DHH + c8];
        }

        f32x4 o[4];
        #pragma unroll
        for (int db = 0; db < 4; db++) o[db] = (f32x4){0.f, 0.f, 0.f, 0.f};
        float m_old[4] = {-1e30f, -1e30f, -1e30f, -1e30f};
        float l_run[4] = {0.f, 0.f, 0.f, 0.f};

        for (int kt = 0; kt <= qi; kt++) {
            __syncthreads();   // prev-iter MFMA LDS reads done (covers Qs on iter 0)
            const ush* Kp = Kb + (size_t)(kt * 64) * DHH;
            #pragma unroll
            for (int it = 0; it < 2; it++) {
                int chunk = it * 256 + tid;
                int r = chunk >> 3, c8 = (chunk & 7) * 8;
                *(bf16x8*)&Ks[r][c8] = *(const bf16x8*)&Kp[r * DHH + c8];
            }
            #pragma unroll
            for (int it = 0; it < 2; it++) {
                int chunk = it * 256 + tid;
                int d = chunk >> 3, c8 = (chunk & 7) * 8;
                *(bf16x8*)&Vt[d][c8] = *(const bf16x8*)&Vtb[(size_t)d * TT + kt * 64 + c8];
            }
            __syncthreads();   // staging visible

            bf16x8 qa0 = *(const bf16x8*)&Qs[w * 16 + n16][quad * 8];
            bf16x8 qa1 = *(const bf16x8*)&Qs[w * 16 + n16][32 + quad * 8];
            f32x4 s[4];
            #pragma unroll
            for (int cb = 0; cb < 4; cb++) {
                bf16x8 kb0 = *(const bf16x8*)&Ks[cb * 16 + n16][quad * 8];
                bf16x8 kb1 = *(const bf16x8*)&Ks[cb * 16 + n16][32 + quad * 8];
                f32x4 acc = (f32x4){0.f, 0.f, 0.f, 0.f};
                acc = __builtin_amdgcn_mfma_f32_16x16x32_bf16(qa0, kb0, acc, 0, 0, 0);
                acc = __builtin_amdgcn_mfma_f32_16x16x32_bf16(qa1, kb1, acc, 0, 0, 0);
                s[cb] = acc;
            }

            const int grow_base = q0 + w * 16 + quad * 4;
            const int gcol_base = kt * 64 + n16;
            #pragma unroll
            for (int reg = 0; reg < 4; reg++) {
                float sv[4];
                float pm = -1e30f;
                #pragma unroll
                for (int cb = 0; cb < 4; cb++) {
                    float v = s[cb][reg] * 0.25f;
                    if (gcol_base + cb * 16 > grow_base + reg) v = -1e10f;
                    sv[cb] = v;
                    pm = fmaxf(pm, v);
                }
                #pragma unroll
                for (int off = 1; off < 16; off <<= 1)
                    pm = fmaxf(pm, __shfl_xor(pm, off));
                float mnew = fmaxf(m_old[reg], pm);
                float alpha = __expf(m_old[reg] - mnew);
                float ps = 0.f;
                #pragma unroll
                for (int cb = 0; cb < 4; cb++) {
                    float p = __expf(sv[cb] - mnew);
                    Ps[w][quad * 4 + reg][cb * 16 + n16] = f2bu(p);
                    ps += p;
                }
                #pragma unroll
                for (int off = 1; off < 16; off <<= 1)
                    ps += __shfl_xor(ps, off);
                l_run[reg] = l_run[reg] * alpha + ps;
                m_old[reg] = mnew;
                #pragma unroll
                for (int db = 0; db < 4; db++) o[db][reg] *= alpha;
            }
            // NO barrier: Ps[w] is read only by wave w (same-wave lgkmcnt ordering)

            bf16x8 pa0 = *(const bf16x8*)&Ps[w][n16][quad * 8];
            bf16x8 pa1 = *(const bf16x8*)&Ps[w][n16][32 + quad * 8];
            #pragma unroll
            for (int db = 0; db < 4; db++) {
                bf16x8 vb0 = *(const bf16x8*)&Vt[db * 16 + n16][quad * 8];
                bf16x8 vb1 = *(const bf16x8*)&Vt[db * 16 + n16][32 + quad * 8];
                o[db] = __builtin_amdgcn_mfma_f32_16x16x32_bf16(pa0, vb0, o[db], 0, 0, 0);
                o[db] = __builtin_amdgcn_mfma_f32_16x16x32_bf16(pa1, vb1, o[db], 0, 0, 0);
            }
        }

        #pragma unroll
        for (int reg = 0; reg < 4; reg++) {
            const float il = 1.0f / l_run[reg];
            const int t_ = q0 + w * 16 + quad * 4 + reg;
            bf16* outr = attn + ((size_t)(b_ * TT + t_)) * DD + h * 64 + n16;
            #pragma unroll
            for (int db = 0; db < 4; db++)
                outr[db * 16] = f2b(o[db][reg] * il);
        }
    }
}

// ---------------------------------------------------------------------------
// Kernel 2 FALLBACK (exact R7 kernel): f32 K/V from d_out.
// ---------------------------------------------------------------------------
__global__ __launch_bounds__(256) void flash_attn_mfma(
    const bf16* __restrict__ qin, const float* __restrict__ kin,
    const float* __restrict__ vin, bf16* __restrict__ attn)
{
    __shared__ __align__(16) ush Qs[64][72];
    __shared__ __align__(16) ush Ks[64][72];
    __shared__ __align__(16) ush Vt[64][72];
    __shared__ __align__(16) ush Ps[4][16][72];

    const int tid  = threadIdx.x;
    const int lane = tid & 63;
    const int w    = tid >> 6;
    const int n16  = lane & 15;
    const int quad = lane >> 4;
    const int qi = blockIdx.x;
    const int bh = blockIdx.y;
    const int q0 = qi * 64;

    const ush*   Qp = (const ush*)qin + ((size_t)bh * TT + q0) * DHH;
    const float* Kb = kin + (size_t)bh * TT * DHH;
    const float* Vb = vin + (size_t)bh * TT * DHH;

    #pragma unroll
    for (int it = 0; it < 4; it++) {
        int idx = (it * 256 + tid) * 4;
        int r = idx >> 6, d = idx & 63;
        *(ushort4*)&Qs[r][d] = *(const ushort4*)&Qp[idx];
    }

    f32x4 o[4];
    #pragma unroll
    for (int db = 0; db < 4; db++) o[db] = (f32x4){0.f, 0.f, 0.f, 0.f};
    float m_old[4] = {-1e30f, -1e30f, -1e30f, -1e30f};
    float l_run[4] = {0.f, 0.f, 0.f, 0.f};

    for (int kt = 0; kt <= qi; kt++) {
        const float* Kp = Kb + (size_t)(kt * 64) * DHH;
        const float* Vp = Vb + (size_t)(kt * 64) * DHH;
        __syncthreads();
        #pragma unroll
        for (int it = 0; it < 4; it++) {
            int idx = (it * 256 + tid) * 4;
            int c = idx >> 6, d = idx & 63;
            float4 kv = *(const float4*)&Kp[idx];
            ushort4 kb;
            kb.x = f2bu(kv.x); kb.y = f2bu(kv.y); kb.z = f2bu(kv.z); kb.w = f2bu(kv.w);
            *(ushort4*)&Ks[c][d] = kb;
        }
        #pragma unroll
        for (int it = 0; it < 4; it++) {
            int c = tid & 63, d0 = (tid >> 6) * 4 + it * 16;
            float4 vv = *(const float4*)&Vp[c * 64 + d0];
            Vt[d0 + 0][c] = f2bu(vv.x);
            Vt[d0 + 1][c] = f2bu(vv.y);
            Vt[d0 + 2][c] = f2bu(vv.z);
            Vt[d0 + 3][c] = f2bu(vv.w);
        }
        __syncthreads();

        bf16x8 qa0 = *(const bf16x8*)&Qs[w * 16 + n16][quad * 8];
        bf16x8 qa1 = *(const bf16x8*)&Qs[w * 16 + n16][32 + quad * 8];
        f32x4 s[4];
        #pragma unroll
        for (int cb = 0; cb < 4; cb++) {
            bf16x8 kb0 = *(const bf16x8*)&Ks[cb * 16 + n16][quad * 8];
            bf16x8 kb1 = *(const bf16x8*)&Ks[cb * 16 + n16][32 + quad * 8];
            f32x4 acc = (f32x4){0.f, 0.f, 0.f, 0.f};
            acc = __builtin_amdgcn_mfma_f32_16x16x32_bf16(qa0, kb0, acc, 0, 0, 0);
            acc = __builtin_amdgcn_mfma_f32_16x16x32_bf16(qa1, kb1, acc, 0, 0, 0);
            s[cb] = acc;
        }

        const int grow_base = q0 + w * 16 + quad * 4;
        const int gcol_base = kt * 64 + n16;
        #pragma unroll
        for (int reg = 0; reg < 4; reg++) {
            float sv[4];
            float pm = -1e30f;
            #pragma unroll
            for (int cb = 0; cb < 4; cb++) {
                float v = s[cb][reg] * 0.25f;
                if (gcol_base + cb * 16 > grow_base + reg) v = -1e10f;
                sv[cb] = v;
                pm = fmaxf(pm, v);
            }
            #pragma unroll
            for (int off = 1; off < 16; off <<= 1)
                pm = fmaxf(pm, __shfl_xor(pm, off));
            float mnew = fmaxf(m_old[reg], pm);
            float alpha = __expf(m_old[reg] - mnew);
            float ps = 0.f;
            #pragma unroll
            for (int cb = 0; cb < 4; cb++) {
                float p = __expf(sv[cb] - mnew);
                Ps[w][quad * 4 + reg][cb * 16 + n16] = f2bu(p);
                ps += p;
            }
            #pragma unroll
            for (int off = 1; off < 16; off <<= 1)
                ps += __shfl_xor(ps, off);
            l_run[reg] = l_run[reg] * alpha + ps;
            m_old[reg] = mnew;
            #pragma unroll
            for (int db = 0; db < 4; db++) o[db][reg] *= alpha;
        }
        __syncthreads();

        bf16x8 pa0 = *(const bf16x8*)&Ps[w][n16][quad * 8];
        bf16x8 pa1 = *(const bf16x8*)&Ps[w][n16][32 + quad * 8];
        #pragma unroll
        for (int db = 0; db < 4; db++) {
            bf16x8 vb0 = *(const bf16x8*)&Vt[db * 16 + n16][quad * 8];
            bf16x8 vb1 = *(const bf16x8*)&Vt[db * 16 + n16][32 + quad * 8];
            o[db] = __builtin_amdgcn_mfma_f32_16x16x32_bf16(pa0, vb0, o[db], 0, 0, 0);
            o[db] = __builtin_amdgcn_mfma_f32_16x16x32_bf16(pa1, vb1, o[db], 0, 0, 0);
        }
    }

    const int b_ = bh >> 4, h = bh & 15;
    #pragma unroll
    for (int reg = 0; reg < 4; reg++) {
        const float il = 1.0f / l_run[reg];
        const int t_ = q0 + w * 16 + quad * 4 + reg;
        bf16* outr = attn + ((size_t)(b_ * TT + t_)) * DD + h * 64 + n16;
        #pragma unroll
        for (int db = 0; db < 4; db++)
            outr[db * 16] = f2b(o[db][reg] * il);
    }
}

// ---------------------------------------------------------------------------
// Kernel 3: proj MFMA GEMM (unchanged).
// ---------------------------------------------------------------------------
__global__ __launch_bounds__(256) void proj_mfma(
    const ush* __restrict__ a, const ush* __restrict__ wpT,
    const float* __restrict__ bias, float* __restrict__ out)
{
    __shared__ __align__(16) ush As[128][40];
    __shared__ __align__(16) ush Bs[128][40];

    const int tid  = threadIdx.x;
    const int lane = tid & 63;
    const int w    = tid >> 6;
    const int n16  = lane & 15;
    const int quad = lane >> 4;
    const int row0 = blockIdx.y * 128;
    const int col0 = blockIdx.x * 128;
    const int wrow = (w >> 1) * 64;
    const int wcol = (w & 1) * 64;

    f32x4 acc[4][4];
    #pragma unroll
    for (int mb = 0; mb < 4; mb++)
        #pragma unroll
        for (int nb = 0; nb < 4; nb++) acc[mb][nb] = (f32x4){0.f,0.f,0.f,0.f};

    for (int kk0 = 0; kk0 < DD; kk0 += 32) {
        __syncthreads();
        #pragma unroll
        for (int it = 0; it < 2; it++) {
            int idx = it * 256 + tid;
            int m = idx >> 2, kc = idx & 3;
            *(bf16x8*)&As[m][kc * 8] =
                *(const bf16x8*)&a[(size_t)(row0 + m) * DD + kk0 + kc * 8];
        }
        #pragma unroll
        for (int it = 0; it < 2; it++) {
            int idx = it * 256 + tid;
            int n = idx >> 2, kc = idx & 3;
            *(bf16x8*)&Bs[n][kc * 8] =
                *(const bf16x8*)&wpT[(size_t)(col0 + n) * DD + kk0 + kc * 8];
        }
        __syncthreads();

        bf16x8 af[4];
        #pragma unroll
        for (int mb = 0; mb < 4; mb++)
            af[mb] = *(const bf16x8*)&As[wrow + mb * 16 + n16][quad * 8];
        #pragma unroll
        for (int nb = 0; nb < 4; nb++) {
            bf16x8 bfr = *(const bf16x8*)&Bs[wcol + nb * 16 + n16][quad * 8];
            #pragma unroll
            for (int mb = 0; mb < 4; mb++)
                acc[mb][nb] = __builtin_amdgcn_mfma_f32_16x16x32_bf16(
                    af[mb], bfr, acc[mb][nb], 0, 0, 0);
        }
    }

    #pragma unroll
    for (int nb = 0; nb < 4; nb++) {
        const int gc = col0 + wcol + nb * 16 + n16;
        const float bv = bias[gc];
        #pragma unroll
        for (int mb = 0; mb < 4; mb++) {
            #pragma unroll
            for (int reg = 0; reg < 4; reg++) {
                const int gr = row0 + wrow + mb * 16 + quad * 4 + reg;
                out[(size_t)gr * DD + gc] = acc[mb][nb][reg] + bv;
            }
        }
    }
}

extern "C" void kernel_launch(void* const* d_in, const int* in_sizes, int n_in,
                              void* d_out, int out_size, void* d_ws, size_t ws_size,
                              hipStream_t stream) {
    const float *x = nullptr, *w_attn = nullptr, *b_attn = nullptr,
                *w_proj = nullptr, *b_proj = nullptr;
    for (int i = 0; i < n_in; i++) {
        switch (in_sizes[i]) {
            case 4194304: x      = (const float*)d_in[i]; break;
            case 3145728: w_attn = (const float*)d_in[i]; break;
            case 3072:    b_attn = (const float*)d_in[i]; break;
            case 1048576: w_proj = (const float*)d_in[i]; break;
            case 1024:    b_proj = (const float*)d_in[i]; break;
            default: break;
        }
    }
    if (!x || !w_attn || !b_attn || !w_proj || !b_proj) return;

    float* out_a = (float*)d_out;
    float* out_k = out_a + (size_t)MM * DD;
    float* out_v = out_k + (size_t)BB * HH * TT * DHH;

    const size_t MB = 1024 * 1024;
    char* wsc = (char*)d_ws;
    // [0,6MB) wT (dead after qkv) / [0,8MB) attnws ; [8,16MB) qws (dead after
    // flash) / [8,10MB) wpT ; fast path adds [16,24MB) kbf, [24,32MB) vtb.
    ush*  wT     = (ush*)(wsc + 0);
    bf16* attnws = (bf16*)(wsc + 0);
    bf16* qws    = (bf16*)(wsc + 8 * MB);
    ush*  wpT    = (ush*)(wsc + 8 * MB);

    if (ws_size >= 32 * MB) {
        ush* kbf = (ush*)(wsc + 16 * MB);
        ush* vtb = (ush*)(wsc + 24 * MB);
        transpose_cvt<<<dim3(N3 / 64, DD / 64), 256, 0, stream>>>(w_attn, wT, DD, N3);
        qkv_mfma<<<dim3(N3 / 128, MM / 128), 256, 0, stream>>>(
            x, wT, b_attn, qws, out_k, out_v, kbf, vtb, 1);
        flash_attn_bf16<<<dim3(TT / 128, BB * HH), 256, 0, stream>>>(
            (const ush*)qws, kbf, vtb, attnws);
        transpose_cvt<<<dim3(DD / 64, DD / 64), 256, 0, stream>>>(w_proj, wpT, DD, DD);
        proj_mfma<<<dim3(DD / 128, MM / 128), 256, 0, stream>>>(
            (const ush*)attnws, wpT, b_proj, out_a);
    } else if (ws_size >= 16 * MB) {
        transpose_cvt<<<dim3(N3 / 64, DD / 64), 256, 0, stream>>>(w_attn, wT, DD, N3);
        qkv_mfma<<<dim3(N3 / 128, MM / 128), 256, 0, stream>>>(
            x, wT, b_attn, qws, out_k, out_v, nullptr, nullptr, 0);
        flash_attn_mfma<<<dim3(TT / 64, BB * HH), 256, 0, stream>>>(
            qws, out_k, out_v, attnws);
        transpose_cvt<<<dim3(DD / 64, DD / 64), 256, 0, stream>>>(w_proj, wpT, DD, DD);
        proj_mfma<<<dim3(DD / 128, MM / 128), 256, 0, stream>>>(
            (const ush*)attnws, wpT, b_proj, out_a);
    }
}